// Round 4
// baseline (2977.168 us; speedup 1.0000x reference)
//
#include <hip/hip_runtime.h>
#include <hip/hip_bf16.h>
#include <cstdint>
#include <cstddef>

#define BATCH  256
#define HID    1024
#define TSTEPS 128
#define NBLK   256
#define NTHR   768   // 12 waves: (n 0..5) x (kh 0..1); each wave does 2 m-tiles

typedef __attribute__((ext_vector_type(8))) short bf16x8;
typedef __attribute__((ext_vector_type(4))) float f32x4;

__device__ inline float bf2f(__hip_bfloat16 h) { return __bfloat162float(h); }

// ---------------------------------------------------------------------------
// prep: pack w_hh (hi+lo split) frag-major with hi/lo interleaved per lane:
//   frag index g = (((jb*6 + n)*32 + c)*64 + l)*2 + part   (8 bf16 per frag)
//   wrow = gate*1024 + jb*32 + ch*16 + (l&15); k = c*32 + (l>>4)*8
//   (gate = n>>1, ch = n&1)
// Also: h0 -> bf16, out prefilled with b_ffn, barrier counters zeroed.
// ---------------------------------------------------------------------------
__global__ void prep_kernel(const float* __restrict__ vectors,
                            const float* __restrict__ w_hh,
                            const float* __restrict__ b_ffn,
                            __hip_bfloat16* __restrict__ h0,
                            __hip_bfloat16* __restrict__ w2,
                            unsigned* __restrict__ bar,
                            float* __restrict__ out)
{
    const long long stride = (long long)gridDim.x * blockDim.x;
    const long long idx = (long long)blockIdx.x * blockDim.x + threadIdx.x;

    const long long NG = 32LL * 6 * 32 * 64 * 2;   // 786432 frags
    for (long long g = idx; g < NG; g += stride) {
        const int part = (int)(g & 1);
        const int l    = (int)((g >> 1) & 63);
        const int c    = (int)((g >> 7) & 31);
        const int nj   = (int)(g >> 12);
        const int n    = nj % 6;
        const int jb   = nj / 6;
        const int gate = n >> 1, ch = n & 1;
        const int wrow = gate * HID + jb * 32 + ch * 16 + (l & 15);
        const int k    = c * 32 + (l >> 4) * 8;
        const float* src = w_hh + (size_t)wrow * HID + k;
        alignas(16) __hip_bfloat16 v[8];
        #pragma unroll
        for (int e = 0; e < 8; ++e) {
            float w = src[e];
            __hip_bfloat16 hi = __float2bfloat16(w);
            v[e] = part ? __float2bfloat16(w - bf2f(hi)) : hi;
        }
        *(bf16x8*)(w2 + g * 8) = *(const bf16x8*)v;
    }

    const long long NH = (long long)BATCH * HID;
    for (long long i = idx; i < NH; i += stride)
        h0[i] = __float2bfloat16(vectors[i]);

    const float bf = b_ffn[0];
    for (long long i = idx; i < (long long)BATCH * TSTEPS; i += stride) out[i] = bf;

    for (long long i = idx; i < 4096; i += stride) bar[i] = 0u;
}

// ---------------------------------------------------------------------------
// Persistent GRU. 256 blocks = 32 jblk (32 cols, 96 w-rows) x 8 mgrp (32 rows).
// jblk co-located per XCD (blk&7): 1.57 MB weights/XCD stay L2-hot.
// 12 waves = 6 n-tiles x 2 K-halves; each wave computes BOTH m-tiles reusing
// its B frags from registers (halves per-CU vmem issue).
// h/x cross-block via SYSTEM-scope atomics; per-m-group 32-block barrier.
// ---------------------------------------------------------------------------
__global__ __launch_bounds__(NTHR)
void gru_persistent(const float* __restrict__ vectors,
                    const float* __restrict__ w_ih,
                    const float* __restrict__ b_ih,
                    const float* __restrict__ b_hh,
                    const float* __restrict__ w_ffn,
                    const float* __restrict__ first_input,
                    __hip_bfloat16* __restrict__ h_a,
                    __hip_bfloat16* __restrict__ h_b,
                    const __hip_bfloat16* __restrict__ w2,
                    unsigned* __restrict__ bar,
                    float* __restrict__ out)
{
    __shared__ alignas(16) unsigned long long ldsA8[8192];  // 64 KB A frags
    __shared__ float ghp[2][3][32][32];                     // 24 KB partial gh
    __shared__ float x_lds[32];

    const int blk  = blockIdx.x;
    const int xcd  = blk & 7, q = blk >> 3;
    const int jblk = xcd * 4 + (q & 3);   // 0..31, co-located per XCD
    const int mgrp = q >> 2;              // 0..7
    const int m_base = mgrp * 32, j_base = jblk * 32;
    const int tid  = threadIdx.x;
    const int lane = tid & 63, wv = tid >> 6;
    const int n    = wv >> 1, kh = wv & 1;
    const int gate = n >> 1, ch = n & 1;
    const int l15  = lane & 15, kg = lane >> 4;
    // A-frag lane slot (pre c-parity XOR): (l15 ^ 2*kg) + 16*kg
    const int aln  = (l15 ^ (kg << 1)) + (kg << 4);

    // epilogue ownership: elems i = tid, tid+768 of 32b x 32jc grid
    float wih_[2][3], bih_[2][3], bhh_[2][3], wf_[2], hreg[2];
    #pragma unroll
    for (int kk = 0; kk < 2; ++kk) {
        int i = tid + kk * NTHR;
        if (i < 1024) {
            int b = i >> 5, jc = i & 31;
            int j = j_base + jc, brow = m_base + b;
            #pragma unroll
            for (int g = 0; g < 3; ++g) {
                wih_[kk][g] = w_ih[g * HID + j];
                bih_[kk][g] = b_ih[g * HID + j];
                bhh_[kk][g] = b_hh[g * HID + j];
            }
            wf_[kk] = w_ffn[j];
            hreg[kk] = vectors[(size_t)brow * HID + j];
        }
    }
    const float x0 = first_input[0];

    const bf16x8* __restrict__ Bb =
        (const bf16x8*)w2 + ((size_t)jblk * 6 + n) * 4096;

    for (int t = 0; t < TSTEPS; ++t) {
        const __hip_bfloat16* hcur = (t & 1) ? h_b : h_a;
        __hip_bfloat16* hnxt = (t & 1) ? h_a : h_b;

        // ---- stage: x + A (32 rows x 1024 k, bf16) into swizzled LDS ----
        if (tid < 32) {
            float xv = x0;
            if (t > 0)
                xv = __hip_atomic_load(&out[(size_t)(m_base + tid) * TSTEPS + t - 1],
                                       __ATOMIC_RELAXED, __HIP_MEMORY_SCOPE_SYSTEM);
            x_lds[tid] = xv;
        }
        const unsigned long long* hsrc =
            (const unsigned long long*)hcur + (size_t)m_base * 256;
        for (int g = tid; g < 8192; g += NTHR) {
            unsigned long long v = __hip_atomic_load(&hsrc[g],
                __ATOMIC_RELAXED, __HIP_MEMORY_SCOPE_SYSTEM);
            int row = g >> 8, ck8 = g & 255;          // 8B chunk within row
            int mt = row >> 4, rr = row & 15;
            int c = ck8 >> 3, kg2 = (ck8 >> 1) & 3, half = ck8 & 1;
            int slot = ((mt << 5) + c) * 64 +
                       ((rr ^ (kg2 << 1) ^ ((c & 1) << 3)) + (kg2 << 4));
            ldsA8[slot * 2 + half] = v;
        }
        __syncthreads();

        // ---- compute: wave (n,kh): 16 c-steps, 2 m-tiles, B in regs ----
        f32x4 acc0 = {0.f, 0.f, 0.f, 0.f};
        f32x4 acc1 = acc0;
        const int c0 = kh * 16;
        #pragma unroll 4
        for (int cc = 0; cc < 16; ++cc) {
            const int c = c0 + cc;
            const bf16x8* __restrict__ pB = Bb + (((size_t)c * 64 + lane) << 1);
            bf16x8 bh = pB[0];
            bf16x8 bl = pB[1];
            const int lo = aln ^ ((c & 1) << 3);
            bf16x8 a0 = *(const bf16x8*)&ldsA8[(size_t)(c * 64 + lo) * 2];
            bf16x8 a1 = *(const bf16x8*)&ldsA8[(size_t)((32 + c) * 64 + lo) * 2];
            acc0 = __builtin_amdgcn_mfma_f32_16x16x32_bf16(a0, bh, acc0, 0, 0, 0);
            acc1 = __builtin_amdgcn_mfma_f32_16x16x32_bf16(a1, bh, acc1, 0, 0, 0);
            acc0 = __builtin_amdgcn_mfma_f32_16x16x32_bf16(a0, bl, acc0, 0, 0, 0);
            acc1 = __builtin_amdgcn_mfma_f32_16x16x32_bf16(a1, bl, acc1, 0, 0, 0);
        }
        {
            const int jc = ch * 16 + l15;
            const int rb = kg * 4;
            #pragma unroll
            for (int r = 0; r < 4; ++r) {
                ghp[kh][gate][rb + r][jc]      = acc0[r];
                ghp[kh][gate][16 + rb + r][jc] = acc1[r];
            }
        }
        __syncthreads();

        // ---- epilogue: gates, h update, h store, y reduce ----
        #pragma unroll
        for (int kk = 0; kk < 2; ++kk) {
            int i = tid + kk * NTHR;
            bool own = i < 1024;
            unsigned hbits = 0; int brow = 0, jc = 0; float py = 0.f;
            if (own) {
                int b = i >> 5; jc = i & 31; brow = m_base + b;
                float x = x_lds[b];
                float ghr = ghp[0][0][b][jc] + ghp[1][0][b][jc] + bhh_[kk][0];
                float ghz = ghp[0][1][b][jc] + ghp[1][1][b][jc] + bhh_[kk][1];
                float ghn = ghp[0][2][b][jc] + ghp[1][2][b][jc] + bhh_[kk][2];
                float gir = fmaf(x, wih_[kk][0], bih_[kk][0]);
                float giz = fmaf(x, wih_[kk][1], bih_[kk][1]);
                float gin = fmaf(x, wih_[kk][2], bih_[kk][2]);
                float rg = 1.f / (1.f + expf(-(gir + ghr)));
                float zg = 1.f / (1.f + expf(-(giz + ghz)));
                float ng = tanhf(fmaf(rg, ghn, gin));
                float hnew = (1.f - zg) * ng + zg * hreg[kk];
                hreg[kk] = hnew;
                __hip_bfloat16 hb = __float2bfloat16(hnew);
                hbits = (unsigned)__builtin_bit_cast(unsigned short, hb);
                py = hnew * wf_[kk];
            }
            unsigned other = (unsigned)__shfl_xor((int)hbits, 1);
            if (own && ((tid & 1) == 0)) {
                unsigned val = (hbits & 0xffffu) | (other << 16);
                __hip_atomic_store((unsigned*)hnxt + (size_t)brow * 512 + ((j_base + jc) >> 1),
                                   val, __ATOMIC_RELAXED, __HIP_MEMORY_SCOPE_SYSTEM);
            }
            py += __shfl_xor(py, 1);
            py += __shfl_xor(py, 2);
            py += __shfl_xor(py, 4);
            py += __shfl_xor(py, 8);
            py += __shfl_xor(py, 16);
            if (own && ((tid & 31) == 0))
                __hip_atomic_fetch_add(&out[(size_t)brow * TSTEPS + t], py,
                                       __ATOMIC_RELAXED, __HIP_MEMORY_SCOPE_SYSTEM);
        }

        // ---- per-m-group barrier: 32 blocks ----
        if (t != TSTEPS - 1) {
            __syncthreads();   // drains each wave's stores before arrive
            if (tid == 0) {
                __hip_atomic_fetch_add(&bar[t * 8 + mgrp], 1u,
                    __ATOMIC_RELEASE, __HIP_MEMORY_SCOPE_SYSTEM);
                while (__hip_atomic_load(&bar[t * 8 + mgrp], __ATOMIC_ACQUIRE,
                                         __HIP_MEMORY_SCOPE_SYSTEM) != 32u)
                    __builtin_amdgcn_s_sleep(2);
            }
            __syncthreads();
        }
    }
}

extern "C" void kernel_launch(void* const* d_in, const int* in_sizes, int n_in,
                              void* d_out, int out_size, void* d_ws, size_t ws_size,
                              hipStream_t stream)
{
    const float* vectors     = (const float*)d_in[0];
    const float* w_ih        = (const float*)d_in[1];
    const float* w_hh        = (const float*)d_in[2];
    const float* b_ih        = (const float*)d_in[3];
    const float* b_hh        = (const float*)d_in[4];
    const float* w_ffn       = (const float*)d_in[5];
    const float* b_ffn       = (const float*)d_in[6];
    const float* first_input = (const float*)d_in[7];
    float* out = (float*)d_out;

    // workspace carve (~13.6 MB)
    char* p = (char*)d_ws;
    __hip_bfloat16* h_a = (__hip_bfloat16*)p;  p += (size_t)BATCH * HID * 2;
    __hip_bfloat16* h_b = (__hip_bfloat16*)p;  p += (size_t)BATCH * HID * 2;
    __hip_bfloat16* w2  = (__hip_bfloat16*)p;  p += 32LL * 6 * 32 * 64 * 2 * 8 * 2;
    unsigned* bar = (unsigned*)p;              p += 4096 * 4;

    prep_kernel<<<1024, 256, 0, stream>>>(vectors, w_hh, b_ffn, h_a, w2, bar, out);

    void* args[] = {
        (void*)&vectors, (void*)&w_ih, (void*)&b_ih, (void*)&b_hh,
        (void*)&w_ffn, (void*)&first_input,
        (void*)&h_a, (void*)&h_b, (void*)&w2, (void*)&bar, (void*)&out
    };
    hipLaunchCooperativeKernel((const void*)gru_persistent,
                               dim3(NBLK), dim3(NTHR), args, 0, stream);
}

// Round 5
// 2025.939 us; speedup vs baseline: 1.4695x; 1.4695x over previous
//
#include <hip/hip_runtime.h>
#include <hip/hip_bf16.h>
#include <cstdint>
#include <cstddef>

#define BATCH  256
#define HID    1024
#define TSTEPS 128
#define NBLK   256
#define NTHR   768   // 12 waves: (n 0..5) x (kh 0..1); each wave does 2 m-tiles

typedef __attribute__((ext_vector_type(8))) short bf16x8;
typedef __attribute__((ext_vector_type(4))) float f32x4;

__device__ inline float bf2f(__hip_bfloat16 h) { return __bfloat162float(h); }

// ---------------------------------------------------------------------------
// prep: pack w_hh (hi bf16 ONLY — the hi/lo split moved to the h side)
// frag-major: frag g = ((jb*6 + n)*32 + c)*64 + l  (8 bf16 per frag)
//   wrow = gate*1024 + jb*32 + ch*16 + (l&15); k = c*32 + (l>>4)*8
//   (gate = n>>1, ch = n&1)
// h0 -> hi/lo bf16 planes; out prefilled with b_ffn; barrier counters zeroed.
// ---------------------------------------------------------------------------
__global__ void prep_kernel(const float* __restrict__ vectors,
                            const float* __restrict__ w_hh,
                            const float* __restrict__ b_ffn,
                            __hip_bfloat16* __restrict__ h_hi0,
                            __hip_bfloat16* __restrict__ h_lo0,
                            __hip_bfloat16* __restrict__ w2,
                            unsigned* __restrict__ bar,
                            float* __restrict__ out)
{
    const long long stride = (long long)gridDim.x * blockDim.x;
    const long long idx = (long long)blockIdx.x * blockDim.x + threadIdx.x;

    const long long NG = 32LL * 6 * 32 * 64;   // 393216 frags (hi only)
    for (long long g = idx; g < NG; g += stride) {
        const int l  = (int)(g & 63);
        const int c  = (int)((g >> 6) & 31);
        const int nj = (int)(g >> 11);
        const int n  = nj % 6;
        const int jb = nj / 6;
        const int gate = n >> 1, ch = n & 1;
        const int wrow = gate * HID + jb * 32 + ch * 16 + (l & 15);
        const int k    = c * 32 + (l >> 4) * 8;
        const float* src = w_hh + (size_t)wrow * HID + k;
        alignas(16) __hip_bfloat16 v[8];
        #pragma unroll
        for (int e = 0; e < 8; ++e) v[e] = __float2bfloat16(src[e]);
        *(bf16x8*)(w2 + g * 8) = *(const bf16x8*)v;
    }

    const long long NH = (long long)BATCH * HID;
    for (long long i = idx; i < NH; i += stride) {
        float h = vectors[i];
        __hip_bfloat16 hi = __float2bfloat16(h);
        h_hi0[i] = hi;
        h_lo0[i] = __float2bfloat16(h - bf2f(hi));
    }
    const float bf = b_ffn[0];
    for (long long i = idx; i < (long long)BATCH * TSTEPS; i += stride) out[i] = bf;
    for (long long i = idx; i < 1024; i += stride) bar[i] = 0u;
}

// ---------------------------------------------------------------------------
// Persistent GRU. 256 blocks = 32 jblk (32 cols, 96 w-rows) x 8 mgrp (32 rows).
// jblk co-located per XCD (blk&7): 786 KB weights/XCD stay L2-hot (and the
// RELAXED barrier never invalidates them — round 4's acq/rel was the bug).
// 12 waves = 6 n-tiles x 2 K-halves; each wave computes BOTH m-tiles and
// reuses ONE B frag for 4 MFMAs: gh = (Hhi + Hlo) * Whi.
// h via SYSTEM-scope (sc0 sc1) IC-coherent loads/stores; per-mgrp barrier.
// ---------------------------------------------------------------------------
__global__ __launch_bounds__(NTHR)
void gru_persistent(const float* __restrict__ vectors,
                    const float* __restrict__ w_ih,
                    const float* __restrict__ b_ih,
                    const float* __restrict__ b_hh,
                    const float* __restrict__ w_ffn,
                    const float* __restrict__ first_input,
                    __hip_bfloat16* __restrict__ h_hi_a,
                    __hip_bfloat16* __restrict__ h_lo_a,
                    __hip_bfloat16* __restrict__ h_hi_b,
                    __hip_bfloat16* __restrict__ h_lo_b,
                    const __hip_bfloat16* __restrict__ w2,
                    unsigned* __restrict__ bar,
                    float* __restrict__ out)
{
    // A planes: [2(part)][32 rows][2048 B], row-major, 16B XOR swizzle per row
    __shared__ alignas(16) unsigned char ldsA[131072];
    __shared__ float ghp[2][3][32][32];   // 24 KB K-half partials
    __shared__ float x_lds[32];

    const int blk  = blockIdx.x;
    const int xcd  = blk & 7, q = blk >> 3;
    const int jblk = xcd * 4 + (q & 3);   // 0..31, co-located per XCD
    const int mgrp = q >> 2;              // 0..7
    const int m_base = mgrp * 32, j_base = jblk * 32;
    const int tid  = threadIdx.x;
    const int lane = tid & 63, wv = tid >> 6;
    const int n    = wv >> 1, kh = wv & 1;
    const int gate = n >> 1, ch = n & 1;
    const int l15  = lane & 15, kg = lane >> 4;

    // A-read swizzle constants: off(c) = ((c^cxr)<<6) | kgx
    const int kgx = ((kg ^ (l15 & 3)) << 4);
    const int cxr = (l15 >> 2) & 1;
    const int ab0 = l15 * 2048;            // mt=0 row base
    const int ab1 = (16 + l15) * 2048;     // mt=1 row base

    // epilogue ownership: elems i = tid, tid+768 of 32b x 32jc grid
    float wih_[2][3], bih_[2][3], bhh_[2][3], wf_[2], hreg[2];
    #pragma unroll
    for (int kk = 0; kk < 2; ++kk) {
        int i = tid + kk * NTHR;
        if (i < 1024) {
            int b = i >> 5, jc = i & 31;
            int j = j_base + jc, brow = m_base + b;
            #pragma unroll
            for (int g = 0; g < 3; ++g) {
                wih_[kk][g] = w_ih[g * HID + j];
                bih_[kk][g] = b_ih[g * HID + j];
                bhh_[kk][g] = b_hh[g * HID + j];
            }
            wf_[kk] = w_ffn[j];
            hreg[kk] = vectors[(size_t)brow * HID + j];
        }
    }
    const float x0 = first_input[0];

    const bf16x8* __restrict__ Bw =
        (const bf16x8*)w2 + (size_t)(jblk * 6 + n) * 2048;

    for (int t = 0; t < TSTEPS; ++t) {
        const __hip_bfloat16* hchi = (t & 1) ? h_hi_b : h_hi_a;
        const __hip_bfloat16* hclo = (t & 1) ? h_lo_b : h_lo_a;
        __hip_bfloat16* hnhi = (t & 1) ? h_hi_a : h_hi_b;
        __hip_bfloat16* hnlo = (t & 1) ? h_lo_a : h_lo_b;

        // ---- stage: x + A hi/lo planes (2 x 64 KB) via 16B sc0sc1 loads ----
        if (tid < 32) {
            float xv = x0;
            if (t > 0)
                xv = __hip_atomic_load(&out[(size_t)(m_base + tid) * TSTEPS + t - 1],
                                       __ATOMIC_RELAXED, __HIP_MEMORY_SCOPE_SYSTEM);
            x_lds[tid] = xv;
        }
        {
            const uint4* srcHi = (const uint4*)(hchi + (size_t)m_base * HID);
            const uint4* srcLo = (const uint4*)(hclo + (size_t)m_base * HID);
            uint4 tmp[11];
            #pragma unroll
            for (int it = 0; it < 11; ++it) {
                int g = tid + it * NTHR;
                if (g < 8192) {
                    const uint4* ap = (g < 4096) ? (srcHi + g) : (srcLo + (g - 4096));
                    asm volatile("global_load_dwordx4 %0, %1, off sc0 sc1"
                                 : "=v"(tmp[it]) : "v"(ap) : "memory");
                }
            }
            asm volatile("s_waitcnt vmcnt(0)" ::: "memory");
            #pragma unroll
            for (int it = 0; it < 11; ++it) {
                int g = tid + it * NTHR;
                if (g < 8192) {
                    int pl  = g >> 12, gg = g & 4095;
                    int row = gg >> 7, k16 = gg & 127;
                    int bo  = pl * 65536 + row * 2048 +
                              ((k16 << 4) ^ ((row & 7) << 4));
                    *(uint4*)(ldsA + bo) = tmp[it];
                }
            }
        }
        __syncthreads();

        // ---- compute: wave (n,kh): 16 c-steps, 1 B-load -> 4 MFMAs ----
        f32x4 acc0 = {0.f, 0.f, 0.f, 0.f};
        f32x4 acc1 = acc0;
        #pragma unroll 4
        for (int cc = 0; cc < 16; ++cc) {
            const int c = (kh << 4) + cc;
            bf16x8 bw = Bw[c * 64 + lane];
            const int off = (((c ^ cxr) << 6) | kgx);
            bf16x8 a0h = *(const bf16x8*)(ldsA + ab0 + off);
            bf16x8 a1h = *(const bf16x8*)(ldsA + ab1 + off);
            bf16x8 a0l = *(const bf16x8*)(ldsA + 65536 + ab0 + off);
            bf16x8 a1l = *(const bf16x8*)(ldsA + 65536 + ab1 + off);
            acc0 = __builtin_amdgcn_mfma_f32_16x16x32_bf16(a0h, bw, acc0, 0, 0, 0);
            acc1 = __builtin_amdgcn_mfma_f32_16x16x32_bf16(a1h, bw, acc1, 0, 0, 0);
            acc0 = __builtin_amdgcn_mfma_f32_16x16x32_bf16(a0l, bw, acc0, 0, 0, 0);
            acc1 = __builtin_amdgcn_mfma_f32_16x16x32_bf16(a1l, bw, acc1, 0, 0, 0);
        }
        {
            const int jc = ch * 16 + l15;
            const int rb = kg * 4;
            #pragma unroll
            for (int r = 0; r < 4; ++r) {
                ghp[kh][gate][rb + r][jc]      = acc0[r];
                ghp[kh][gate][16 + rb + r][jc] = acc1[r];
            }
        }
        __syncthreads();

        // ---- epilogue: gates, h update, hi/lo h store, y reduce ----
        #pragma unroll
        for (int kk = 0; kk < 2; ++kk) {
            int i = tid + kk * NTHR;
            bool own = i < 1024;
            unsigned hib = 0, lob = 0; int brow = 0, jc = 0; float py = 0.f;
            if (own) {
                int b = i >> 5; jc = i & 31; brow = m_base + b;
                float x = x_lds[b];
                float ghr = ghp[0][0][b][jc] + ghp[1][0][b][jc] + bhh_[kk][0];
                float ghz = ghp[0][1][b][jc] + ghp[1][1][b][jc] + bhh_[kk][1];
                float ghn = ghp[0][2][b][jc] + ghp[1][2][b][jc] + bhh_[kk][2];
                float gir = fmaf(x, wih_[kk][0], bih_[kk][0]);
                float giz = fmaf(x, wih_[kk][1], bih_[kk][1]);
                float gin = fmaf(x, wih_[kk][2], bih_[kk][2]);
                float rg = 1.f / (1.f + expf(-(gir + ghr)));
                float zg = 1.f / (1.f + expf(-(giz + ghz)));
                float ng = tanhf(fmaf(rg, ghn, gin));
                float hnew = (1.f - zg) * ng + zg * hreg[kk];
                hreg[kk] = hnew;
                __hip_bfloat16 hb = __float2bfloat16(hnew);
                __hip_bfloat16 lb = __float2bfloat16(hnew - bf2f(hb));
                hib = (unsigned)__builtin_bit_cast(unsigned short, hb);
                lob = (unsigned)__builtin_bit_cast(unsigned short, lb);
                py = hnew * wf_[kk];
            }
            unsigned hi_o = (unsigned)__shfl_xor((int)hib, 1);
            unsigned lo_o = (unsigned)__shfl_xor((int)lob, 1);
            if (own && ((tid & 1) == 0)) {
                size_t idx32 = (size_t)brow * 512 + ((j_base + jc) >> 1);
                __hip_atomic_store((unsigned*)hnhi + idx32, (hib & 0xffffu) | (hi_o << 16),
                                   __ATOMIC_RELAXED, __HIP_MEMORY_SCOPE_SYSTEM);
                __hip_atomic_store((unsigned*)hnlo + idx32, (lob & 0xffffu) | (lo_o << 16),
                                   __ATOMIC_RELAXED, __HIP_MEMORY_SCOPE_SYSTEM);
            }
            py += __shfl_xor(py, 1);
            py += __shfl_xor(py, 2);
            py += __shfl_xor(py, 4);
            py += __shfl_xor(py, 8);
            py += __shfl_xor(py, 16);
            if (own && ((tid & 31) == 0))
                __hip_atomic_fetch_add(&out[(size_t)brow * TSTEPS + t], py,
                                       __ATOMIC_RELAXED, __HIP_MEMORY_SCOPE_SYSTEM);
        }

        // ---- per-m-group barrier: 32 blocks, RELAXED (no cache maintenance;
        //      __syncthreads' vmcnt(0) drain + IC write-through give order) ----
        if (t != TSTEPS - 1) {
            __syncthreads();
            if (tid == 0) {
                __hip_atomic_fetch_add(&bar[t * 8 + mgrp], 1u,
                    __ATOMIC_RELAXED, __HIP_MEMORY_SCOPE_SYSTEM);
                while (__hip_atomic_load(&bar[t * 8 + mgrp], __ATOMIC_RELAXED,
                                         __HIP_MEMORY_SCOPE_SYSTEM) != 32u)
                    __builtin_amdgcn_s_sleep(1);
            }
            __syncthreads();
        }
    }
}

extern "C" void kernel_launch(void* const* d_in, const int* in_sizes, int n_in,
                              void* d_out, int out_size, void* d_ws, size_t ws_size,
                              hipStream_t stream)
{
    const float* vectors     = (const float*)d_in[0];
    const float* w_ih        = (const float*)d_in[1];
    const float* w_hh        = (const float*)d_in[2];
    const float* b_ih        = (const float*)d_in[3];
    const float* b_hh        = (const float*)d_in[4];
    const float* w_ffn       = (const float*)d_in[5];
    const float* b_ffn       = (const float*)d_in[6];
    const float* first_input = (const float*)d_in[7];
    float* out = (float*)d_out;

    // workspace carve (~8.3 MB)
    char* p = (char*)d_ws;
    __hip_bfloat16* h_hi_a = (__hip_bfloat16*)p;  p += (size_t)BATCH * HID * 2;
    __hip_bfloat16* h_lo_a = (__hip_bfloat16*)p;  p += (size_t)BATCH * HID * 2;
    __hip_bfloat16* h_hi_b = (__hip_bfloat16*)p;  p += (size_t)BATCH * HID * 2;
    __hip_bfloat16* h_lo_b = (__hip_bfloat16*)p;  p += (size_t)BATCH * HID * 2;
    __hip_bfloat16* w2 = (__hip_bfloat16*)p;      p += 32LL * 6 * 32 * 64 * 8 * 2;
    unsigned* bar = (unsigned*)p;                 p += 1024 * 4;

    prep_kernel<<<1024, 256, 0, stream>>>(vectors, w_hh, b_ffn,
                                          h_hi_a, h_lo_a, w2, bar, out);

    void* args[] = {
        (void*)&vectors, (void*)&w_ih, (void*)&b_ih, (void*)&b_hh,
        (void*)&w_ffn, (void*)&first_input,
        (void*)&h_hi_a, (void*)&h_lo_a, (void*)&h_hi_b, (void*)&h_lo_b,
        (void*)&w2, (void*)&bar, (void*)&out
    };
    hipLaunchCooperativeKernel((const void*)gru_persistent,
                               dim3(NBLK), dim3(NTHR), args, 0, stream);
}

// Round 6
// 1740.618 us; speedup vs baseline: 1.7104x; 1.1639x over previous
//
#include <hip/hip_runtime.h>
#include <hip/hip_bf16.h>
#include <cstdint>
#include <cstddef>

#define BATCH  256
#define HID    1024
#define TSTEPS 128
#define NBLK   256
#define NTHR   512   // 8 waves = 2 ngrp (3 n-tiles each) x 4 kh (8 c-steps each)

typedef __attribute__((ext_vector_type(8))) short bf16x8;
typedef __attribute__((ext_vector_type(4))) float f32x4;

__device__ inline float bf2f(__hip_bfloat16 h) { return __bfloat162float(h); }

#define MFMA(a, b, c) __builtin_amdgcn_mfma_f32_16x16x32_bf16((a), (b), (c), 0, 0, 0)

// ---------------------------------------------------------------------------
// prep: pack w_hh (plain bf16) frag-major:
//   frag g = ((jb*6 + n)*32 + c)*64 + l   (8 bf16 per frag)
//   wrow = gate*1024 + jb*32 + ch*16 + (l&15); k = c*32 + (l>>4)*8
//   (gate = n>>1, ch = n&1)
// h0 -> bf16 (single plane); out prefilled with b_ffn; barrier zeroed.
// ---------------------------------------------------------------------------
__global__ void prep_kernel(const float* __restrict__ vectors,
                            const float* __restrict__ w_hh,
                            const float* __restrict__ b_ffn,
                            __hip_bfloat16* __restrict__ h0,
                            __hip_bfloat16* __restrict__ w2,
                            unsigned* __restrict__ bar,
                            float* __restrict__ out)
{
    const long long stride = (long long)gridDim.x * blockDim.x;
    const long long idx = (long long)blockIdx.x * blockDim.x + threadIdx.x;

    const long long NG = 32LL * 6 * 32 * 64;   // 393216 frags
    for (long long g = idx; g < NG; g += stride) {
        const int l  = (int)(g & 63);
        const int c  = (int)((g >> 6) & 31);
        const int nj = (int)(g >> 11);
        const int n  = nj % 6;
        const int jb = nj / 6;
        const int gate = n >> 1, ch = n & 1;
        const int wrow = gate * HID + jb * 32 + ch * 16 + (l & 15);
        const int k    = c * 32 + (l >> 4) * 8;
        const float* src = w_hh + (size_t)wrow * HID + k;
        alignas(16) __hip_bfloat16 v[8];
        #pragma unroll
        for (int e = 0; e < 8; ++e) v[e] = __float2bfloat16(src[e]);
        *(bf16x8*)(w2 + g * 8) = *(const bf16x8*)v;
    }

    const long long NH = (long long)BATCH * HID;
    for (long long i = idx; i < NH; i += stride)
        h0[i] = __float2bfloat16(vectors[i]);

    const float bf = b_ffn[0];
    for (long long i = idx; i < (long long)BATCH * TSTEPS; i += stride) out[i] = bf;
    for (long long i = idx; i < 1024; i += stride) bar[i] = 0u;
}

// ---------------------------------------------------------------------------
// Persistent GRU. 256 blocks = 32 jblk (32 cols, 96 w-rows) x 8 mgrp (32 rows).
// jblk co-located per XCD (blk&7): 786 KB weights/XCD stay L2-hot.
// 8 waves = 2 ngrp x 4 kh. Per c-iter per wave: 2 A ds_reads -> 3 B L2-loads
// -> 6 MFMAs (A-LDS reads per CU-step: 128, conflict-free; was 768 + conflicts).
// Pure-bf16 A (fp32 h master in regs). K-partials in LDS (stride-36, 2-way).
// h/x via RELAXED system-scope atomics; per-mgrp 32-block barrier (r5 protocol).
// ---------------------------------------------------------------------------
__global__ __launch_bounds__(NTHR)
void gru_persistent(const float* __restrict__ vectors,
                    const float* __restrict__ w_ih,
                    const float* __restrict__ b_ih,
                    const float* __restrict__ b_hh,
                    const float* __restrict__ w_ffn,
                    const float* __restrict__ first_input,
                    __hip_bfloat16* __restrict__ h_a,
                    __hip_bfloat16* __restrict__ h_b,
                    const __hip_bfloat16* __restrict__ w2,
                    unsigned* __restrict__ bar,
                    float* __restrict__ out)
{
    __shared__ alignas(16) unsigned char ldsA[65536];  // A: [32 rows][2KB] swizzled
    __shared__ float ghp[4][3][32][36];                // 54 KB K-partials (2-way free)
    __shared__ float x_lds[32];

    const int blk  = blockIdx.x;
    const int xcd  = blk & 7, q = blk >> 3;
    const int jblk = xcd * 4 + (q & 3);   // 0..31, co-located per XCD
    const int mgrp = q >> 2;              // 0..7
    const int m_base = mgrp * 32, j_base = jblk * 32;
    const int tid  = threadIdx.x;
    const int lane = tid & 63, wv = tid >> 6;
    const int ngrp = wv & 1, kh = wv >> 1;      // 2 n-groups x 4 K-splits
    const int l15  = lane & 15, kg = lane >> 4;

    // epilogue: every thread owns 2 elems of the 32x32 (b,jc) grid
    float wih_[2][3], bih_[2][3], bhh_[2][3], wf_[2], hreg[2];
    #pragma unroll
    for (int kk = 0; kk < 2; ++kk) {
        int i = tid + kk * NTHR;
        int b = i >> 5, jc = i & 31;
        int j = j_base + jc, brow = m_base + b;
        #pragma unroll
        for (int g = 0; g < 3; ++g) {
            wih_[kk][g] = w_ih[g * HID + j];
            bih_[kk][g] = b_ih[g * HID + j];
            bhh_[kk][g] = b_hh[g * HID + j];
        }
        wf_[kk] = w_ffn[j];
        hreg[kk] = vectors[(size_t)brow * HID + j];
    }
    const float x0 = first_input[0];

    // B frag pointers for this wave's 3 n-tiles (lane folded in)
    const bf16x8* __restrict__ Bp0 =
        (const bf16x8*)w2 + ((size_t)(jblk * 6 + ngrp * 3 + 0) * 32) * 64 + lane;
    const bf16x8* __restrict__ Bp1 =
        (const bf16x8*)w2 + ((size_t)(jblk * 6 + ngrp * 3 + 1) * 32) * 64 + lane;
    const bf16x8* __restrict__ Bp2 =
        (const bf16x8*)w2 + ((size_t)(jblk * 6 + ngrp * 3 + 2) * 32) * 64 + lane;

    for (int t = 0; t < TSTEPS; ++t) {
        const __hip_bfloat16* hcur = (t & 1) ? h_b : h_a;
        __hip_bfloat16* hnxt = (t & 1) ? h_a : h_b;

        // ---- stage: x + A (32 rows x 1024 bf16 = 64 KB) via 16B sc0sc1 ----
        if (tid < 32) {
            float xv = x0;
            if (t > 0)
                xv = __hip_atomic_load(&out[(size_t)(m_base + tid) * TSTEPS + t - 1],
                                       __ATOMIC_RELAXED, __HIP_MEMORY_SCOPE_SYSTEM);
            x_lds[tid] = xv;
        }
        {
            const uint4* srcA = (const uint4*)(hcur + (size_t)m_base * HID);
            uint4 tmp[8];
            #pragma unroll
            for (int it = 0; it < 8; ++it) {
                int g = tid + it * NTHR;   // < 4096 always
                asm volatile("global_load_dwordx4 %0, %1, off sc0 sc1"
                             : "=v"(tmp[it]) : "v"(srcA + g) : "memory");
            }
            asm volatile("s_waitcnt vmcnt(0)" ::: "memory");
            #pragma unroll
            for (int it = 0; it < 8; ++it) {
                int g = tid + it * NTHR;
                int row = g >> 7, k16 = g & 127;
                int bo = row * 2048 + ((k16 << 4) ^ ((row & 7) << 4));
                *(uint4*)(ldsA + bo) = tmp[it];
            }
        }
        __syncthreads();

        // ---- compute: 8 c-steps x [2 A-reads, 3 B-loads, 6 MFMAs] ----
        f32x4 acc00 = {0.f,0.f,0.f,0.f}, acc01 = acc00, acc10 = acc00,
              acc11 = acc00, acc20 = acc00, acc21 = acc00;
        {
            const int swz = (l15 & 7) << 4;
            const int rb0 = l15 * 2048, rb1 = (16 + l15) * 2048;
            #pragma unroll
            for (int cc = 0; cc < 8; ++cc) {
                const int c = (kh << 3) + cc;
                bf16x8 b0 = Bp0[c * 64];
                bf16x8 b1 = Bp1[c * 64];
                bf16x8 b2 = Bp2[c * 64];
                const int colb = ((c << 6) | (kg << 4)) ^ swz;
                bf16x8 a0 = *(const bf16x8*)(ldsA + rb0 + colb);
                bf16x8 a1 = *(const bf16x8*)(ldsA + rb1 + colb);
                acc00 = MFMA(a0, b0, acc00);  acc01 = MFMA(a1, b0, acc01);
                acc10 = MFMA(a0, b1, acc10);  acc11 = MFMA(a1, b1, acc11);
                acc20 = MFMA(a0, b2, acc20);  acc21 = MFMA(a1, b2, acc21);
            }
        }
        // K-partial store: C/D layout col=l15, row=kg*4+r
        {
            const int n0 = ngrp * 3;
            #pragma unroll
            for (int r = 0; r < 4; ++r) {
                const int rw0 = kg * 4 + r, rw1 = 16 + kg * 4 + r;
                ghp[kh][(n0    ) >> 1][rw0][(((n0    ) & 1) << 4) + l15] = acc00[r];
                ghp[kh][(n0    ) >> 1][rw1][(((n0    ) & 1) << 4) + l15] = acc01[r];
                ghp[kh][(n0 + 1) >> 1][rw0][(((n0 + 1) & 1) << 4) + l15] = acc10[r];
                ghp[kh][(n0 + 1) >> 1][rw1][(((n0 + 1) & 1) << 4) + l15] = acc11[r];
                ghp[kh][(n0 + 2) >> 1][rw0][(((n0 + 2) & 1) << 4) + l15] = acc20[r];
                ghp[kh][(n0 + 2) >> 1][rw1][(((n0 + 2) & 1) << 4) + l15] = acc21[r];
            }
        }
        __syncthreads();

        // ---- epilogue: gates, h update, h store, y reduce ----
        #pragma unroll
        for (int kk = 0; kk < 2; ++kk) {
            const int i = tid + kk * NTHR;
            const int b = i >> 5, jc = i & 31;
            const int brow = m_base + b;
            const float x = x_lds[b];
            float ghr = bhh_[kk][0], ghz = bhh_[kk][1], ghn = bhh_[kk][2];
            #pragma unroll
            for (int p = 0; p < 4; ++p) {
                ghr += ghp[p][0][b][jc];
                ghz += ghp[p][1][b][jc];
                ghn += ghp[p][2][b][jc];
            }
            const float gir = fmaf(x, wih_[kk][0], bih_[kk][0]);
            const float giz = fmaf(x, wih_[kk][1], bih_[kk][1]);
            const float gin = fmaf(x, wih_[kk][2], bih_[kk][2]);
            const float rg = 1.f / (1.f + expf(-(gir + ghr)));
            const float zg = 1.f / (1.f + expf(-(giz + ghz)));
            const float ng = tanhf(fmaf(rg, ghn, gin));
            const float hnew = (1.f - zg) * ng + zg * hreg[kk];
            hreg[kk] = hnew;
            const unsigned hbits =
                (unsigned)__builtin_bit_cast(unsigned short, __float2bfloat16(hnew));
            const unsigned other = (unsigned)__shfl_xor((int)hbits, 1);
            if ((tid & 1) == 0) {
                __hip_atomic_store(
                    (unsigned*)hnxt + (size_t)brow * 512 + ((j_base + jc) >> 1),
                    (hbits & 0xffffu) | (other << 16),
                    __ATOMIC_RELAXED, __HIP_MEMORY_SCOPE_SYSTEM);
            }
            float py = hnew * wf_[kk];
            py += __shfl_xor(py, 1);
            py += __shfl_xor(py, 2);
            py += __shfl_xor(py, 4);
            py += __shfl_xor(py, 8);
            py += __shfl_xor(py, 16);
            if ((tid & 31) == 0)
                __hip_atomic_fetch_add(&out[(size_t)brow * TSTEPS + t], py,
                                       __ATOMIC_RELAXED, __HIP_MEMORY_SCOPE_SYSTEM);
        }

        // ---- per-m-group barrier: 32 blocks, RELAXED (r5-proven protocol) ----
        if (t != TSTEPS - 1) {
            __syncthreads();   // drains vmcnt: h stores + y atomics done at IC
            if (tid == 0) {
                __hip_atomic_fetch_add(&bar[t * 8 + mgrp], 1u,
                    __ATOMIC_RELAXED, __HIP_MEMORY_SCOPE_SYSTEM);
                while (__hip_atomic_load(&bar[t * 8 + mgrp], __ATOMIC_RELAXED,
                                         __HIP_MEMORY_SCOPE_SYSTEM) != 32u)
                    __builtin_amdgcn_s_sleep(1);
            }
            __syncthreads();
        }
    }
}

extern "C" void kernel_launch(void* const* d_in, const int* in_sizes, int n_in,
                              void* d_out, int out_size, void* d_ws, size_t ws_size,
                              hipStream_t stream)
{
    const float* vectors     = (const float*)d_in[0];
    const float* w_ih        = (const float*)d_in[1];
    const float* w_hh        = (const float*)d_in[2];
    const float* b_ih        = (const float*)d_in[3];
    const float* b_hh        = (const float*)d_in[4];
    const float* w_ffn       = (const float*)d_in[5];
    const float* b_ffn       = (const float*)d_in[6];
    const float* first_input = (const float*)d_in[7];
    float* out = (float*)d_out;

    // workspace carve (~7.4 MB)
    char* p = (char*)d_ws;
    __hip_bfloat16* h_a = (__hip_bfloat16*)p;  p += (size_t)BATCH * HID * 2;
    __hip_bfloat16* h_b = (__hip_bfloat16*)p;  p += (size_t)BATCH * HID * 2;
    __hip_bfloat16* w2  = (__hip_bfloat16*)p;  p += 32LL * 6 * 32 * 64 * 8 * 2;
    unsigned* bar = (unsigned*)p;              p += 1024 * 4;

    prep_kernel<<<1024, 256, 0, stream>>>(vectors, w_hh, b_ffn, h_a, w2, bar, out);

    void* args[] = {
        (void*)&vectors, (void*)&w_ih, (void*)&b_ih, (void*)&b_hh,
        (void*)&w_ffn, (void*)&first_input,
        (void*)&h_a, (void*)&h_b, (void*)&w2, (void*)&bar, (void*)&out
    };
    hipLaunchCooperativeKernel((const void*)gru_persistent,
                               dim3(NBLK), dim3(NTHR), args, 0, stream);
}

// Round 8
// 593.991 us; speedup vs baseline: 5.0121x; 2.9304x over previous
//
#include <hip/hip_runtime.h>
#include <hip/hip_bf16.h>
#include <cstdint>
#include <cstddef>

#define BATCH  256
#define HID    1024
#define TSTEPS 128
#define NBLK   256
#define NTHR   512   // 8 waves = 2 ngrp (3 n-tiles) x 4 kh (8 c-steps)

typedef __attribute__((ext_vector_type(8))) short bf16x8;
typedef __attribute__((ext_vector_type(4))) float f32x4;

__device__ inline float bf2f(__hip_bfloat16 h) { return __bfloat162float(h); }

#define MFMA(a, b, c) __builtin_amdgcn_mfma_f32_16x16x32_bf16((a), (b), (c), 0, 0, 0)

// ---------------------------------------------------------------------------
// prep: pack w_hh (bf16) frag-major (as r6):
//   frag g = ((jb*6 + n)*32 + c)*64 + l ; wrow = gate*1024+jb*32+ch*16+(l&15);
//   k = c*32 + (l>>4)*8   (gate=n>>1, ch=n&1)
// h0 -> bf16; flag array zeroed.
// ---------------------------------------------------------------------------
__global__ void prep_kernel(const float* __restrict__ vectors,
                            const float* __restrict__ w_hh,
                            __hip_bfloat16* __restrict__ h0,
                            __hip_bfloat16* __restrict__ w2,
                            unsigned* __restrict__ bar)
{
    const long long stride = (long long)gridDim.x * blockDim.x;
    const long long idx = (long long)blockIdx.x * blockDim.x + threadIdx.x;

    const long long NG = 32LL * 6 * 32 * 64;
    for (long long g = idx; g < NG; g += stride) {
        const int l  = (int)(g & 63);
        const int c  = (int)((g >> 6) & 31);
        const int nj = (int)(g >> 11);
        const int n  = nj % 6;
        const int jb = nj / 6;
        const int gate = n >> 1, ch = n & 1;
        const int wrow = gate * HID + jb * 32 + ch * 16 + (l & 15);
        const int k    = c * 32 + (l >> 4) * 8;
        const float* src = w_hh + (size_t)wrow * HID + k;
        alignas(16) __hip_bfloat16 v[8];
        #pragma unroll
        for (int e = 0; e < 8; ++e) v[e] = __float2bfloat16(src[e]);
        *(bf16x8*)(w2 + g * 8) = *(const bf16x8*)v;
    }

    const long long NH = (long long)BATCH * HID;
    for (long long i = idx; i < NH; i += stride)
        h0[i] = __float2bfloat16(vectors[i]);

    for (long long i = idx; i < 1024; i += stride) bar[i] = 0u;
}

// ---------------------------------------------------------------------------
// Persistent GRU. 256 blocks = 32 jblk (32 cols/96 w-rows) x 8 mgrp (32 rows).
// Weights live ENTIRELY in registers (24 frags = 96 VGPR per lane, loaded once).
// y (= next x) computed locally per block from staged h_t via 2 extra MFMAs/cc
// (wffn as masked B-frag) -> out leaves the sync domain; jblk==0 writes it.
// Cross-block: h (packed 8B system-scope atomic stores) + RMW-free flag barrier.
// ---------------------------------------------------------------------------
__global__ __launch_bounds__(NTHR, 2)
void gru_persistent(const float* __restrict__ vectors,
                    const float* __restrict__ w_ih,
                    const float* __restrict__ b_ih,
                    const float* __restrict__ b_hh,
                    const float* __restrict__ w_ffn,
                    const float* __restrict__ b_ffn,
                    const float* __restrict__ first_input,
                    __hip_bfloat16* __restrict__ h_a,
                    __hip_bfloat16* __restrict__ h_b,
                    const __hip_bfloat16* __restrict__ w2,
                    unsigned* __restrict__ bar,
                    float* __restrict__ out)
{
    __shared__ alignas(16) unsigned char ldsA[65536];        // h_t staged, swizzled
    __shared__ float ghp[4][3][32][36];                      // gh K-partials
    __shared__ float ghy[4][32];                             // y K-partials
    __shared__ alignas(16) __hip_bfloat16 hstage[1024];      // h_{t+1} out-stage
    __shared__ __hip_bfloat16 wffn_lds[1024];

    const int blk  = blockIdx.x;
    const int xcd  = blk & 7, q = blk >> 3;
    const int jblk = xcd * 4 + (q & 3);
    const int mgrp = q >> 2;
    const int m_base = mgrp * 32, j_base = jblk * 32;
    const int tid  = threadIdx.x;
    const int lane = tid & 63, wv = tid >> 6;
    const int ngrp = wv & 1, kh = wv >> 1;
    const int l15  = lane & 15, kg = lane >> 4;

    // per-thread epilogue constants (2 owned elems of the 32x32 (b,jc) grid)
    float wih_[2][3], bih_[2][3], bhh_[2][3], hreg[2];
    #pragma unroll
    for (int kk = 0; kk < 2; ++kk) {
        int i = tid + kk * NTHR;
        int b = i >> 5, jc = i & 31;
        int j = j_base + jc, brow = m_base + b;
        #pragma unroll
        for (int g = 0; g < 3; ++g) {
            wih_[kk][g] = w_ih[g * HID + j];
            bih_[kk][g] = b_ih[g * HID + j];
            bhh_[kk][g] = b_hh[g * HID + j];
        }
        hreg[kk] = vectors[(size_t)brow * HID + j];
    }
    const float x0  = first_input[0];
    const float bff = b_ffn[0];

    for (int i = tid; i < 1024; i += NTHR)
        wffn_lds[i] = __float2bfloat16(w_ffn[i]);

    // B weights -> registers, permanently (24 frags = 96 VGPRs)
    bf16x8 Breg[3][8];
    {
        const bf16x8* w2f = (const bf16x8*)w2;
        #pragma unroll
        for (int nn = 0; nn < 3; ++nn)
            #pragma unroll
            for (int cc = 0; cc < 8; ++cc)
                Breg[nn][cc] =
                    w2f[((size_t)(jblk * 6 + ngrp * 3 + nn) * 32 + kh * 8 + cc) * 64 + lane];
    }

    const int swz = (l15 & 7) << 4;
    const int rb0 = l15 * 2048, rb1 = (16 + l15) * 2048;
    const bf16x8 zb = {0, 0, 0, 0, 0, 0, 0, 0};

    for (int t = 0; t <= TSTEPS; ++t) {
        // ---- wait for h_t (flags from iter t-1), then stage it ----
        if (t > 0 && wv == 0) {
            const unsigned fidx = (unsigned)(mgrp * 32 + (lane & 31));
            while (__hip_atomic_load(&bar[fidx], __ATOMIC_RELAXED,
                                     __HIP_MEMORY_SCOPE_SYSTEM) < (unsigned)t)
                __builtin_amdgcn_s_sleep(1);
        }
        __syncthreads();

        const __hip_bfloat16* hcur = (t & 1) ? h_b : h_a;
        __hip_bfloat16* hnxt = (t & 1) ? h_a : h_b;
        {
            const uint4* srcA = (const uint4*)(hcur + (size_t)m_base * HID);
            uint4 tmp[8];
            #pragma unroll
            for (int it = 0; it < 8; ++it) {
                int g = tid + it * NTHR;
                asm volatile("global_load_dwordx4 %0, %1, off sc0 sc1"
                             : "=v"(tmp[it]) : "v"(srcA + g) : "memory");
            }
            asm volatile("s_waitcnt vmcnt(0)" ::: "memory");
            #pragma unroll
            for (int it = 0; it < 8; ++it) {
                int g = tid + it * NTHR;
                int row = g >> 7, k16 = g & 127;
                int bo = row * 2048 + ((k16 << 4) ^ ((row & 7) << 4));
                *(uint4*)(ldsA + bo) = tmp[it];
            }
        }
        __syncthreads();

        if (t < TSTEPS) {
            // ---- GEMM (B from regs) + local y-MFMA ----
            f32x4 acc00 = {0.f,0.f,0.f,0.f}, acc01 = acc00, acc10 = acc00,
                  acc11 = acc00, acc20 = acc00, acc21 = acc00;
            f32x4 accy0 = acc00, accy1 = acc00;
            #pragma unroll
            for (int cc = 0; cc < 8; ++cc) {
                const int c = (kh << 3) + cc;
                const int colb = ((c << 6) | (kg << 4)) ^ swz;
                bf16x8 a0 = *(const bf16x8*)(ldsA + rb0 + colb);
                bf16x8 a1 = *(const bf16x8*)(ldsA + rb1 + colb);
                acc00 = MFMA(a0, Breg[0][cc], acc00);
                acc01 = MFMA(a1, Breg[0][cc], acc01);
                acc10 = MFMA(a0, Breg[1][cc], acc10);
                acc11 = MFMA(a1, Breg[1][cc], acc11);
                acc20 = MFMA(a0, Breg[2][cc], acc20);
                acc21 = MFMA(a1, Breg[2][cc], acc21);
                if (ngrp == 0 && t > 0) {
                    bf16x8 wfv = *(const bf16x8*)(wffn_lds + c * 32 + kg * 8);
                    bf16x8 wb = (l15 == 0) ? wfv : zb;
                    accy0 = MFMA(a0, wb, accy0);
                    accy1 = MFMA(a1, wb, accy1);
                }
            }
            {
                const int n0 = ngrp * 3;
                #pragma unroll
                for (int r = 0; r < 4; ++r) {
                    const int rw0 = kg * 4 + r, rw1 = 16 + kg * 4 + r;
                    ghp[kh][(n0    ) >> 1][rw0][(((n0    ) & 1) << 4) + l15] = acc00[r];
                    ghp[kh][(n0    ) >> 1][rw1][(((n0    ) & 1) << 4) + l15] = acc01[r];
                    ghp[kh][(n0 + 1) >> 1][rw0][(((n0 + 1) & 1) << 4) + l15] = acc10[r];
                    ghp[kh][(n0 + 1) >> 1][rw1][(((n0 + 1) & 1) << 4) + l15] = acc11[r];
                    ghp[kh][(n0 + 2) >> 1][rw0][(((n0 + 2) & 1) << 4) + l15] = acc20[r];
                    ghp[kh][(n0 + 2) >> 1][rw1][(((n0 + 2) & 1) << 4) + l15] = acc21[r];
                }
                if (ngrp == 0 && t > 0 && l15 == 0) {
                    #pragma unroll
                    for (int r = 0; r < 4; ++r) {
                        ghy[kh][kg * 4 + r]      = accy0[r];
                        ghy[kh][16 + kg * 4 + r] = accy1[r];
                    }
                }
            }
            __syncthreads();

            // ---- epilogue: x local, gates, h update, out (leader) ----
            #pragma unroll
            for (int kk = 0; kk < 2; ++kk) {
                const int i = tid + kk * NTHR;
                const int b = i >> 5, jc = i & 31;
                const int brow = m_base + b;
                const float x = (t == 0) ? x0
                    : (ghy[0][b] + ghy[1][b] + ghy[2][b] + ghy[3][b] + bff);
                float ghr = bhh_[kk][0], ghz = bhh_[kk][1], ghn = bhh_[kk][2];
                #pragma unroll
                for (int p = 0; p < 4; ++p) {
                    ghr += ghp[p][0][b][jc];
                    ghz += ghp[p][1][b][jc];
                    ghn += ghp[p][2][b][jc];
                }
                const float gir = fmaf(x, wih_[kk][0], bih_[kk][0]);
                const float giz = fmaf(x, wih_[kk][1], bih_[kk][1]);
                const float gin = fmaf(x, wih_[kk][2], bih_[kk][2]);
                const float rg = 1.f / (1.f + expf(-(gir + ghr)));
                const float zg = 1.f / (1.f + expf(-(giz + ghz)));
                const float ng = tanhf(fmaf(rg, ghn, gin));
                const float hnew = (1.f - zg) * ng + zg * hreg[kk];
                hreg[kk] = hnew;
                hstage[b * 32 + jc] = __float2bfloat16(hnew);
                if (t > 0 && jblk == 0 && jc == 0)
                    out[(size_t)brow * TSTEPS + (t - 1)] = x;
            }
            __syncthreads();

            // ---- packed h_{t+1} stores (256 x 8B, system scope) + flag ----
            if (tid < 256) {
                const int b = tid >> 3, off = tid & 7;
                unsigned long long v =
                    *(const unsigned long long*)((const char*)hstage + b * 64 + off * 8);
                __hip_atomic_store(
                    (unsigned long long*)(hnxt + (size_t)(m_base + b) * HID + j_base + off * 4),
                    v, __ATOMIC_RELAXED, __HIP_MEMORY_SCOPE_SYSTEM);
            }
            __syncthreads();   // vmcnt(0) drain: h stores visible at IC
            if (tid == 0)
                __hip_atomic_store(&bar[mgrp * 32 + jblk], (unsigned)(t + 1),
                                   __ATOMIC_RELAXED, __HIP_MEMORY_SCOPE_SYSTEM);
        } else {
            // ---- t == TSTEPS: final y only ----
            if (ngrp == 0) {
                f32x4 accy0 = {0.f,0.f,0.f,0.f}, accy1 = accy0;
                #pragma unroll
                for (int cc = 0; cc < 8; ++cc) {
                    const int c = (kh << 3) + cc;
                    const int colb = ((c << 6) | (kg << 4)) ^ swz;
                    bf16x8 a0 = *(const bf16x8*)(ldsA + rb0 + colb);
                    bf16x8 a1 = *(const bf16x8*)(ldsA + rb1 + colb);
                    bf16x8 wfv = *(const bf16x8*)(wffn_lds + c * 32 + kg * 8);
                    bf16x8 wb = (l15 == 0) ? wfv : zb;
                    accy0 = MFMA(a0, wb, accy0);
                    accy1 = MFMA(a1, wb, accy1);
                }
                if (l15 == 0) {
                    #pragma unroll
                    for (int r = 0; r < 4; ++r) {
                        ghy[kh][kg * 4 + r]      = accy0[r];
                        ghy[kh][16 + kg * 4 + r] = accy1[r];
                    }
                }
            }
            __syncthreads();
            if (jblk == 0 && tid < 32) {
                const float x = ghy[0][tid] + ghy[1][tid] + ghy[2][tid]
                              + ghy[3][tid] + bff;
                out[(size_t)(m_base + tid) * TSTEPS + (TSTEPS - 1)] = x;
            }
        }
    }
}

extern "C" void kernel_launch(void* const* d_in, const int* in_sizes, int n_in,
                              void* d_out, int out_size, void* d_ws, size_t ws_size,
                              hipStream_t stream)
{
    const float* vectors     = (const float*)d_in[0];
    const float* w_ih        = (const float*)d_in[1];
    const float* w_hh        = (const float*)d_in[2];
    const float* b_ih        = (const float*)d_in[3];
    const float* b_hh        = (const float*)d_in[4];
    const float* w_ffn       = (const float*)d_in[5];
    const float* b_ffn       = (const float*)d_in[6];
    const float* first_input = (const float*)d_in[7];
    float* out = (float*)d_out;

    // workspace carve (~7.4 MB)
    char* p = (char*)d_ws;
    __hip_bfloat16* h_a = (__hip_bfloat16*)p;  p += (size_t)BATCH * HID * 2;
    __hip_bfloat16* h_b = (__hip_bfloat16*)p;  p += (size_t)BATCH * HID * 2;
    __hip_bfloat16* w2  = (__hip_bfloat16*)p;  p += 32LL * 6 * 32 * 64 * 8 * 2;
    unsigned* bar = (unsigned*)p;              p += 1024 * 4;

    prep_kernel<<<1024, 256, 0, stream>>>(vectors, w_hh, h_a, w2, bar);

    void* args[] = {
        (void*)&vectors, (void*)&w_ih, (void*)&b_ih, (void*)&b_hh,
        (void*)&w_ffn, (void*)&b_ffn, (void*)&first_input,
        (void*)&h_a, (void*)&h_b, (void*)&w2, (void*)&bar, (void*)&out
    };
    hipError_t err = hipLaunchCooperativeKernel((const void*)gru_persistent,
                               dim3(NBLK), dim3(NTHR), args, 0, stream);
    (void)err;
}